// Round 5
// baseline (666.484 us; speedup 1.0000x reference)
//
#include <hip/hip_runtime.h>
#include <hip/hip_bf16.h>
#include <math.h>

// HebbianPlasticLayer: B=DIN=DOUT=4096, fp32 in/out.
// out = y + eta*tanh(y)*s,  y = x@W.T + bias,  s = (x*x/||x||)@sigmoid(alpha).T
// Round 5: PHASE-SPLIT dual GEMM. Each phase uses 64x64-per-wave tiles
// (LDS reads 0.031 B/FLOP vs R4's 0.046 -> lifts the LDS-read ceiling) while
// only one 64-reg accumulator is live at a time -> 4 waves/SIMD retained.
// y round-trips through out[] (L2-hot, same thread) with a __threadfence()
// to order the same-thread global RAW. BK=64 + XOR swizzle (0 conflicts) kept.

typedef __attribute__((ext_vector_type(4))) float floatx4;
typedef __attribute__((ext_vector_type(8))) short shortx8;

#define MAT_N 4096
#define MAT_ELEMS ((size_t)MAT_N * MAT_N)

__device__ __forceinline__ unsigned short f2bf(float f) {
    unsigned int u = __float_as_uint(f);
    unsigned int r = (u + 0x7fffu + ((u >> 16) & 1u)) >> 16;   // RNE
    return (unsigned short)r;
}

__device__ __forceinline__ void gload_lds16(const unsigned short* gptr, unsigned short* lptr) {
    __builtin_amdgcn_global_load_lds(
        (const __attribute__((address_space(1))) unsigned int*)gptr,
        (__attribute__((address_space(3))) unsigned int*)lptr,
        16, 0, 0);
}

// ---------- merged conversion kernel ----------
__global__ __launch_bounds__(256) void conv_all_kernel(const float* __restrict__ x,
                                                       const float* __restrict__ W,
                                                       const float* __restrict__ alpha,
                                                       unsigned short* __restrict__ xb,
                                                       unsigned short* __restrict__ pb,
                                                       unsigned short* __restrict__ wb,
                                                       unsigned short* __restrict__ ab) {
    if (blockIdx.x < MAT_N) {
        const int row = blockIdx.x;
        const float4* xr = (const float4*)(x + (size_t)row * MAT_N);
        float4 v[4];
        float s = 0.f;
#pragma unroll
        for (int i = 0; i < 4; i++) {
            v[i] = xr[threadIdx.x + i * 256];
            s += v[i].x * v[i].x + v[i].y * v[i].y + v[i].z * v[i].z + v[i].w * v[i].w;
        }
        for (int off = 32; off > 0; off >>= 1) s += __shfl_down(s, off, 64);
        __shared__ float red[4];
        if ((threadIdx.x & 63) == 0) red[threadIdx.x >> 6] = s;
        __syncthreads();
        const float inv = 1.0f / (sqrtf(red[0] + red[1] + red[2] + red[3]) + 1e-8f);
        unsigned short* xrow = xb + (size_t)row * MAT_N;
        unsigned short* prow = pb + (size_t)row * MAT_N;
#pragma unroll
        for (int i = 0; i < 4; i++) {
            float e[4] = {v[i].x, v[i].y, v[i].z, v[i].w};
            ushort4 xo, po;
            xo.x = f2bf(e[0]); xo.y = f2bf(e[1]); xo.z = f2bf(e[2]); xo.w = f2bf(e[3]);
            po.x = f2bf(e[0] * e[0] * inv); po.y = f2bf(e[1] * e[1] * inv);
            po.z = f2bf(e[2] * e[2] * inv); po.w = f2bf(e[3] * e[3] * inv);
            *(ushort4*)(xrow + (threadIdx.x + i * 256) * 4) = xo;
            *(ushort4*)(prow + (threadIdx.x + i * 256) * 4) = po;
        }
    } else {
        size_t base = ((size_t)(blockIdx.x - MAT_N) * 256 + threadIdx.x) * 8;
        const float4* wp = (const float4*)(W + base);
        const float4* ap = (const float4*)(alpha + base);
        float4 w0 = wp[0], w1 = wp[1], a0 = ap[0], a1 = ap[1];
        float wv[8] = {w0.x, w0.y, w0.z, w0.w, w1.x, w1.y, w1.z, w1.w};
        float av[8] = {a0.x, a0.y, a0.z, a0.w, a1.x, a1.y, a1.z, a1.w};
        shortx8 wo, ao;
#pragma unroll
        for (int j = 0; j < 8; j++) {
            wo[j] = (short)f2bf(wv[j]);
            ao[j] = (short)f2bf(1.0f / (1.0f + __expf(-av[j])));
        }
        *(shortx8*)(wb + base) = wo;
        *(shortx8*)(ab + base) = ao;
    }
}

// ---------- phase-split dual GEMM, 256 threads, 64x64/wave, BK=64, swizzled ----------
// LDS layout per buffer: [row 0..127][kc' 0..7] 16B chunks, row stride 128B;
// chunk (row,kc) at kc' = kc ^ (row&7).  Staging: thread t -> row_s = t>>3
// (0..31), slot = t&7, global kc = slot^(row_s&7); issue i adds 32 rows.
__global__ __launch_bounds__(256, 4) void fused_gemm_kernel(
    const unsigned short* __restrict__ X,
    const unsigned short* __restrict__ Wb,
    const unsigned short* __restrict__ P,
    const unsigned short* __restrict__ Ab,
    const float* __restrict__ bias,
    const float* __restrict__ eta_p,
    float* __restrict__ out) {
    constexpr int K = MAT_N;
    constexpr int N = MAT_N;
    constexpr int BK = 64;
    __shared__ __align__(16) unsigned short sA0[128 * BK];   // 16 KB
    __shared__ __align__(16) unsigned short sB0[128 * BK];   // 16 KB

    const int tid = threadIdx.x;
    const int row0 = blockIdx.y * 128;
    const int col0 = blockIdx.x * 128;
    const int lane = tid & 63;
    const int wave = tid >> 6;          // 0..3, 2x2 wave grid, 64x64 each
    const int wm = (wave >> 1) * 64;
    const int wn = (wave & 1) * 64;
    const int quad = lane >> 4;
    const int l16 = lane & 15;

    const int row_s = tid >> 3;                        // 0..31
    const int kc_g  = (tid & 7) ^ (row_s & 7);
    const size_t arow = (size_t)(row0 + row_s) * K + kc_g * 8;
    const size_t brow = (size_t)(col0 + row_s) * K + kc_g * 8;

    floatx4 acc[4][4];

    // ================= phase 1: Y = X @ Wb^T =================
#pragma unroll
    for (int i = 0; i < 4; i++)
#pragma unroll
        for (int j = 0; j < 4; j++) acc[i][j] = (floatx4){0.f, 0.f, 0.f, 0.f};

    for (int k0 = 0; k0 < K; k0 += BK) {
#pragma unroll
        for (int i = 0; i < 4; i++) {
            const size_t go = (size_t)i * 32 * K + k0;
            const int lo = i * 2048 + tid * 8;
            gload_lds16(X + arow + go, sA0 + lo);
            gload_lds16(Wb + brow + go, sB0 + lo);
        }
        __syncthreads();
#pragma unroll
        for (int s = 0; s < 2; s++) {
            const int kcp = ((s * 4 + quad) ^ (l16 & 7)) * 8;
            shortx8 af[4], bfr[4];
#pragma unroll
            for (int i = 0; i < 4; i++)
                af[i] = *(const shortx8*)(sA0 + (wm + i * 16 + l16) * BK + kcp);
#pragma unroll
            for (int j = 0; j < 4; j++)
                bfr[j] = *(const shortx8*)(sB0 + (wn + j * 16 + l16) * BK + kcp);
#pragma unroll
            for (int i = 0; i < 4; i++)
#pragma unroll
                for (int j = 0; j < 4; j++)
                    acc[i][j] = __builtin_amdgcn_mfma_f32_16x16x32_bf16(af[i], bfr[j], acc[i][j], 0, 0, 0);
        }
        __syncthreads();
    }

    // epilogue 1: stash y = acc + bias into out (L2-resident; same thread reads back)
#pragma unroll
    for (int i = 0; i < 4; i++)
#pragma unroll
        for (int j = 0; j < 4; j++)
#pragma unroll
            for (int r = 0; r < 4; r++) {
                int grow = row0 + wm + i * 16 + quad * 4 + r;
                int gcol = col0 + wn + j * 16 + l16;
                out[(size_t)grow * N + gcol] = acc[i][j][r] + bias[gcol];
            }
    __threadfence();   // order same-thread global RAW (store -> much-later load)

    // ================= phase 2: S = P @ Ab^T =================
#pragma unroll
    for (int i = 0; i < 4; i++)
#pragma unroll
        for (int j = 0; j < 4; j++) acc[i][j] = (floatx4){0.f, 0.f, 0.f, 0.f};

    for (int k0 = 0; k0 < K; k0 += BK) {
#pragma unroll
        for (int i = 0; i < 4; i++) {
            const size_t go = (size_t)i * 32 * K + k0;
            const int lo = i * 2048 + tid * 8;
            gload_lds16(P + arow + go, sA0 + lo);
            gload_lds16(Ab + brow + go, sB0 + lo);
        }
        __syncthreads();
#pragma unroll
        for (int s = 0; s < 2; s++) {
            const int kcp = ((s * 4 + quad) ^ (l16 & 7)) * 8;
            shortx8 af[4], bfr[4];
#pragma unroll
            for (int i = 0; i < 4; i++)
                af[i] = *(const shortx8*)(sA0 + (wm + i * 16 + l16) * BK + kcp);
#pragma unroll
            for (int j = 0; j < 4; j++)
                bfr[j] = *(const shortx8*)(sB0 + (wn + j * 16 + l16) * BK + kcp);
#pragma unroll
            for (int i = 0; i < 4; i++)
#pragma unroll
                for (int j = 0; j < 4; j++)
                    acc[i][j] = __builtin_amdgcn_mfma_f32_16x16x32_bf16(af[i], bfr[j], acc[i][j], 0, 0, 0);
        }
        __syncthreads();
    }

    // epilogue 2: combine
    const float eta = *eta_p;
#pragma unroll
    for (int i = 0; i < 4; i++)
#pragma unroll
        for (int j = 0; j < 4; j++)
#pragma unroll
            for (int r = 0; r < 4; r++) {
                int grow = row0 + wm + i * 16 + quad * 4 + r;
                int gcol = col0 + wn + j * 16 + l16;
                size_t idx = (size_t)grow * N + gcol;
                float y = out[idx];
                out[idx] = y + eta * tanhf(y) * acc[i][j][r];
            }
}

extern "C" void kernel_launch(void* const* d_in, const int* in_sizes, int n_in,
                              void* d_out, int out_size, void* d_ws, size_t ws_size,
                              hipStream_t stream) {
    const float* x     = (const float*)d_in[0];
    const float* W     = (const float*)d_in[1];
    const float* alpha = (const float*)d_in[2];
    const float* eta   = (const float*)d_in[3];
    const float* bias  = (const float*)d_in[4];
    float* out = (float*)d_out;

    // workspace layout: xb | pb | wb | ab  (4x32MB bf16) = 128MB
    unsigned short* xb = (unsigned short*)d_ws;
    unsigned short* pb = xb + MAT_ELEMS;
    unsigned short* wb = pb + MAT_ELEMS;
    unsigned short* ab = wb + MAT_ELEMS;

    conv_all_kernel<<<MAT_N + MAT_ELEMS / (8 * 256), 256, 0, stream>>>(x, W, alpha, xb, pb, wb, ab);

    dim3 grid(MAT_N / 128, MAT_N / 128);
    fused_gemm_kernel<<<grid, 256, 0, stream>>>(xb, wb, pb, ab, bias, eta, out);
}

// Round 6
// 466.325 us; speedup vs baseline: 1.4292x; 1.4292x over previous
//
#include <hip/hip_runtime.h>
#include <hip/hip_bf16.h>
#include <math.h>

// HebbianPlasticLayer: B=DIN=DOUT=4096, fp32 in/out.
// out = y + eta*tanh(y)*s,  y = x@W.T + bias,  s = (x*x/||x||)@sigmoid(alpha).T
// Round 6: R4 fused dual-GEMM structure (LDS-BW saturated at 321us) with the
// S-GEMM operands in FP8 e4m3 (error-tolerant path): P8 = fp8(x^2) (row norm
// deferred to epilogue via atomic sumsq), A8 = fp8(sigmoid(alpha)).
// LDS traffic per K-step: 260KB -> 192KB (-26%). fp8 LDS rows are 64B with an
// even-mask slot swizzle (r&6) -> 2-way conflicts only (free per m136).

typedef __attribute__((ext_vector_type(4))) float floatx4;
typedef __attribute__((ext_vector_type(8))) short shortx8;

#define MAT_N 4096
#define MAT_ELEMS ((size_t)MAT_N * MAT_N)

__device__ __forceinline__ unsigned short f2bf(float f) {
    unsigned int u = __float_as_uint(f);
    unsigned int r = (u + 0x7fffu + ((u >> 16) & 1u)) >> 16;   // RNE
    return (unsigned short)r;
}

__device__ __forceinline__ void gload_lds16(const void* gptr, void* lptr) {
    __builtin_amdgcn_global_load_lds(
        (const __attribute__((address_space(1))) unsigned int*)gptr,
        (__attribute__((address_space(3))) unsigned int*)lptr,
        16, 0, 0);
}

// ---------- convert x: xb = bf16(x), p8 = fp8(x^2), sumsq[row] += x^2 ----------
__global__ __launch_bounds__(512) void convx_kernel(const float* __restrict__ x,
                                                    unsigned short* __restrict__ xb,
                                                    unsigned char* __restrict__ p8,
                                                    float* __restrict__ sumsq) {
    size_t base = ((size_t)blockIdx.x * 512 + threadIdx.x) * 8;
    const float4* xp = (const float4*)(x + base);
    float4 a = xp[0], b = xp[1];
    float v[8] = {a.x, a.y, a.z, a.w, b.x, b.y, b.z, b.w};
    shortx8 xo;
    float sq[8];
    float s = 0.f;
#pragma unroll
    for (int j = 0; j < 8; j++) {
        xo[j] = (short)f2bf(v[j]);
        sq[j] = v[j] * v[j];
        s += sq[j];
    }
    *(shortx8*)(xb + base) = xo;
    int p0 = __builtin_amdgcn_cvt_pk_fp8_f32(sq[0], sq[1], 0, false);
    p0 = __builtin_amdgcn_cvt_pk_fp8_f32(sq[2], sq[3], p0, true);
    int p1 = __builtin_amdgcn_cvt_pk_fp8_f32(sq[4], sq[5], 0, false);
    p1 = __builtin_amdgcn_cvt_pk_fp8_f32(sq[6], sq[7], p1, true);
    int2 pv = {p0, p1};
    *(int2*)(p8 + base) = pv;
    // wave covers 512 contiguous elems -> single row (4096/row)
    for (int off = 32; off > 0; off >>= 1) s += __shfl_down(s, off, 64);
    if ((threadIdx.x & 63) == 0) atomicAdd(&sumsq[base >> 12], s);
}

// ---------- convert W,alpha: wb = bf16(W), a8 = fp8(sigmoid(alpha)) ----------
__global__ __launch_bounds__(512) void convwa_kernel(const float* __restrict__ W,
                                                     const float* __restrict__ alpha,
                                                     unsigned short* __restrict__ wb,
                                                     unsigned char* __restrict__ a8) {
    size_t base = ((size_t)blockIdx.x * 512 + threadIdx.x) * 8;
    const float4* wp = (const float4*)(W + base);
    const float4* ap = (const float4*)(alpha + base);
    float4 w0 = wp[0], w1 = wp[1], a0 = ap[0], a1 = ap[1];
    float wv[8] = {w0.x, w0.y, w0.z, w0.w, w1.x, w1.y, w1.z, w1.w};
    float av[8] = {a0.x, a0.y, a0.z, a0.w, a1.x, a1.y, a1.z, a1.w};
    shortx8 wo;
    float sg[8];
#pragma unroll
    for (int j = 0; j < 8; j++) {
        wo[j] = (short)f2bf(wv[j]);
        sg[j] = 1.0f / (1.0f + __expf(-av[j]));
    }
    *(shortx8*)(wb + base) = wo;
    int p0 = __builtin_amdgcn_cvt_pk_fp8_f32(sg[0], sg[1], 0, false);
    p0 = __builtin_amdgcn_cvt_pk_fp8_f32(sg[2], sg[3], p0, true);
    int p1 = __builtin_amdgcn_cvt_pk_fp8_f32(sg[4], sg[5], 0, false);
    p1 = __builtin_amdgcn_cvt_pk_fp8_f32(sg[6], sg[7], p1, true);
    int2 pv = {p0, p1};
    *(int2*)(a8 + base) = pv;
}

// ---------- fused dual-GEMM: Y in bf16, S in fp8, 512 threads, BK=64 ----------
// bf16 LDS: rows 128B, 16B-chunk swizzle kc' = kc ^ (row&7)  (R3, 0 conflicts).
// fp8 LDS: rows 64B, 8B-slot swizzle slot' = slot ^ (row&6) (even mask so the
// 16B staging store covers an intact slot pair; 2-way conflicts = free).
__global__ __launch_bounds__(512, 4) void fused_gemm_kernel(
    const unsigned short* __restrict__ X,
    const unsigned short* __restrict__ Wb,
    const unsigned char* __restrict__ P8,
    const unsigned char* __restrict__ A8,
    const float* __restrict__ bias,
    const float* __restrict__ eta_p,
    const float* __restrict__ sumsq,
    float* __restrict__ out) {
    constexpr int K = MAT_N;
    constexpr int N = MAT_N;
    __shared__ __align__(16) unsigned short sX[128 * 64];   // 16 KB
    __shared__ __align__(16) unsigned short sW[128 * 64];   // 16 KB
    __shared__ __align__(16) unsigned char  sP[128 * 64];   // 8 KB
    __shared__ __align__(16) unsigned char  sA[128 * 64];   // 8 KB

    const int tid = threadIdx.x;
    const int row0 = blockIdx.y * 128;
    const int col0 = blockIdx.x * 128;
    const int lane = tid & 63;
    const int wave = tid >> 6;           // 0..7
    const int wm = (wave >> 1) * 32;     // 4x2 wave grid: 32-row x 64-col
    const int wn = (wave & 1) * 64;
    const int quad = lane >> 4;
    const int l16 = lane & 15;

    floatx4 accY[2][4], accS[2][4];
#pragma unroll
    for (int i = 0; i < 2; i++)
#pragma unroll
        for (int j = 0; j < 4; j++) {
            accY[i][j] = (floatx4){0.f, 0.f, 0.f, 0.f};
            accS[i][j] = (floatx4){0.f, 0.f, 0.f, 0.f};
        }

    // bf16 staging: thread t -> row_s = t>>3 (0..63), chunk = t&7, 2 issues
    const int row_s = tid >> 3;
    const int kc_g  = (tid & 7) ^ (row_s & 7);
    const size_t arow = (size_t)(row0 + row_s) * K + kc_g * 8;
    const size_t brow = (size_t)(col0 + row_s) * K + kc_g * 8;
    // fp8 staging: thread t -> r8 = t>>2 (0..127), 16B chunk c8 = t&3, 1 issue
    const int r8 = tid >> 2;
    const int slot8 = (2 * (tid & 3)) ^ (r8 & 6);
    const size_t prow = (size_t)(row0 + r8) * K + slot8 * 8;   // bytes==elems
    const size_t qrow = (size_t)(col0 + r8) * K + slot8 * 8;

    for (int k0 = 0; k0 < K; k0 += 64) {
#pragma unroll
        for (int i = 0; i < 2; i++) {
            const size_t go = (size_t)i * 64 * K + k0;
            const int lo = i * 4096 + tid * 8;
            gload_lds16(X + arow + go, sX + lo);
            gload_lds16(Wb + brow + go, sW + lo);
        }
        gload_lds16(P8 + prow + k0, sP + tid * 16);
        gload_lds16(A8 + qrow + k0, sA + tid * 16);
        __syncthreads();

#pragma unroll
        for (int s = 0; s < 2; s++) {
            const int kcp = ((s * 4 + quad) ^ (l16 & 7)) * 8;       // bf16, shorts
            const int lsp = ((s * 4 + quad) ^ (l16 & 6)) * 8;       // fp8, bytes
            {
                shortx8 af[2], bfr[4];
#pragma unroll
                for (int i = 0; i < 2; i++)
                    af[i] = *(const shortx8*)(sX + (wm + i * 16 + l16) * 64 + kcp);
#pragma unroll
                for (int j = 0; j < 4; j++)
                    bfr[j] = *(const shortx8*)(sW + (wn + j * 16 + l16) * 64 + kcp);
#pragma unroll
                for (int i = 0; i < 2; i++)
#pragma unroll
                    for (int j = 0; j < 4; j++)
                        accY[i][j] = __builtin_amdgcn_mfma_f32_16x16x32_bf16(af[i], bfr[j], accY[i][j], 0, 0, 0);
            }
            {
                long ap[2], bp[4];
#pragma unroll
                for (int i = 0; i < 2; i++)
                    ap[i] = *(const long*)(sP + (wm + i * 16 + l16) * 64 + lsp);
#pragma unroll
                for (int j = 0; j < 4; j++)
                    bp[j] = *(const long*)(sA + (wn + j * 16 + l16) * 64 + lsp);
#pragma unroll
                for (int i = 0; i < 2; i++)
#pragma unroll
                    for (int j = 0; j < 4; j++)
                        accS[i][j] = __builtin_amdgcn_mfma_f32_16x16x32_fp8_fp8(ap[i], bp[j], accS[i][j], 0, 0, 0);
            }
        }
        __syncthreads();
    }

    const float eta = *eta_p;
#pragma unroll
    for (int i = 0; i < 2; i++) {
#pragma unroll
        for (int r = 0; r < 4; r++) {
            const int grow = row0 + wm + i * 16 + quad * 4 + r;
            const float invn = 1.0f / (sqrtf(sumsq[grow]) + 1e-8f);
#pragma unroll
            for (int j = 0; j < 4; j++) {
                // C/D layout: row = quad*4 + r, col = lane&15   [m89/m91 verified]
                const int gcol = col0 + wn + j * 16 + l16;
                float y = accY[i][j][r] + bias[gcol];
                float s = accS[i][j][r] * invn;
                out[(size_t)grow * N + gcol] = y + eta * tanhf(y) * s;
            }
        }
    }
}

extern "C" void kernel_launch(void* const* d_in, const int* in_sizes, int n_in,
                              void* d_out, int out_size, void* d_ws, size_t ws_size,
                              hipStream_t stream) {
    const float* x     = (const float*)d_in[0];
    const float* W     = (const float*)d_in[1];
    const float* alpha = (const float*)d_in[2];
    const float* eta   = (const float*)d_in[3];
    const float* bias  = (const float*)d_in[4];
    float* out = (float*)d_out;

    // ws: sumsq f32[4096] (16KB pad) | xb 32MB | wb 32MB | p8 16MB | a8 16MB
    char* ws = (char*)d_ws;
    float* sumsq = (float*)ws;
    unsigned short* xb = (unsigned short*)(ws + 16384);
    unsigned short* wb = xb + MAT_ELEMS;
    unsigned char*  p8 = (unsigned char*)(wb + MAT_ELEMS);
    unsigned char*  a8 = p8 + MAT_ELEMS;

    hipMemsetAsync(sumsq, 0, MAT_N * sizeof(float), stream);
    convx_kernel<<<MAT_ELEMS / (8 * 512), 512, 0, stream>>>(x, xb, p8, sumsq);
    convwa_kernel<<<MAT_ELEMS / (8 * 512), 512, 0, stream>>>(W, alpha, wb, a8);

    dim3 grid(MAT_N / 128, MAT_N / 128);
    fused_gemm_kernel<<<grid, 512, 0, stream>>>(xb, wb, p8, a8, bias, eta, sumsq, out);
}